// Round 6
// baseline (901.552 us; speedup 1.0000x reference)
//
#include <hip/hip_runtime.h>
#include <hip/hip_bf16.h>

// GetAffs: seg [1,1,4096,4096] f32 (integer labels), out [8,4096,4096] f32.
// out[o][i][j] = (zeroext(seg)[i+ox][j+oy] == seg[i][j]) ? 1.0f : 0.0f
// OFFSETS: (-1,0),(0,-1),(-2,0),(0,-2),(-4,0),(0,-4),(-8,0),(0,-8)
//
// R5 = MEASUREMENT ROUND: exact R2 kernel (ring + NT stores, 8 planes/block)
// replicated 4x via grid.z (distinct blocks write identical bytes — benign
// race). Purpose: push our dispatch above the harness fills' ~343 us so it
// shows up in the top-5 rocprof rows with FETCH/WRITE/occupancy counters,
// and extract true kernel time K = (bench - 578)/3.

#define IMG_H 4096
#define IMG_W 4096
#define BAND  16

typedef float floatx4 __attribute__((ext_vector_type(4)));

__device__ __forceinline__ float4 ld4(const float* p) { return *(const float4*)p; }

__device__ __forceinline__ void st4_nt(float* p, float4 v) {
    floatx4 x = { v.x, v.y, v.z, v.w };
    __builtin_nontemporal_store(x, (floatx4*)p);
}

__device__ __forceinline__ float4 eq4(float4 a, float4 b) {
    return make_float4(a.x == b.x ? 1.0f : 0.0f,
                       a.y == b.y ? 1.0f : 0.0f,
                       a.z == b.z ? 1.0f : 0.0f,
                       a.w == b.w ? 1.0f : 0.0f);
}

__global__ __launch_bounds__(256) void GetAffs_83416854823610_kernel(
        const float* __restrict__ seg, float* __restrict__ out) {
    const int jq = blockIdx.x * 256 + threadIdx.x;  // float4 column group
    const int j  = jq << 2;                         // first of 4 cols
    const int i0 = blockIdx.y * BAND;               // first row of band
    const float4 zero4 = make_float4(0.f, 0.f, 0.f, 0.f);

    // blockIdx.z in 0..3: identical replicas (measurement only).

    float4 hist[8];
#pragma unroll
    for (int k = 0; k < 8; ++k) {                   // rows i0-8 .. i0-1
        const int r = i0 - 8 + k;                   // slot (r - i0) & 7 = k
        hist[k] = (r >= 0) ? ld4(seg + (size_t)r * IMG_W + j) : zero4;
    }

    const size_t HW = (size_t)IMG_H * IMG_W;

#pragma unroll
    for (int u = 0; u < BAND; ++u) {                // row i = i0 + u
        const int i = i0 + u;
        const float* row = seg + (size_t)i * IMG_W;
        const float4 c  = ld4(row + j);
        const float4 l1 = (j >= 4) ? ld4(row + j - 4) : zero4;
        const float4 l2 = (j >= 8) ? ld4(row + j - 8) : zero4;

        const float4 v1 = hist[(u + 7) & 7];        // row i-1
        const float4 v2 = hist[(u + 6) & 7];        // row i-2
        const float4 v4 = hist[(u + 4) & 7];        // row i-4
        const float4 v8 = hist[u & 7];              // row i-8

        const float4 h1 = make_float4(l1.w, c.x, c.y, c.z);
        const float4 h2 = make_float4(l1.z, l1.w, c.x, c.y);
        const float4 h4 = l1;
        const float4 h8 = l2;

        const size_t base = (size_t)i * IMG_W + (size_t)j;
        st4_nt(out + 0 * HW + base, eq4(v1, c));
        st4_nt(out + 1 * HW + base, eq4(h1, c));
        st4_nt(out + 2 * HW + base, eq4(v2, c));
        st4_nt(out + 3 * HW + base, eq4(h2, c));
        st4_nt(out + 4 * HW + base, eq4(v4, c));
        st4_nt(out + 5 * HW + base, eq4(h4, c));
        st4_nt(out + 6 * HW + base, eq4(v8, c));
        st4_nt(out + 7 * HW + base, eq4(h8, c));

        hist[u & 7] = c;                            // row i replaces row i-8
    }
}

extern "C" void kernel_launch(void* const* d_in, const int* in_sizes, int n_in,
                              void* d_out, int out_size, void* d_ws, size_t ws_size,
                              hipStream_t stream) {
    const float* seg = (const float*)d_in[0];
    float* out = (float*)d_out;
    // x: 4 col-blocks; y: 256 bands; z: 4 identical replicas (measurement).
    dim3 grid((IMG_W / 4) / 256, IMG_H / BAND, 4);
    dim3 block(256);
    GetAffs_83416854823610_kernel<<<grid, block, 0, stream>>>(seg, out);
}

// Round 7
// 596.527 us; speedup vs baseline: 1.5113x; 1.5113x over previous
//
#include <hip/hip_runtime.h>
#include <hip/hip_bf16.h>

// GetAffs: seg [1,1,4096,4096] f32 (integer labels), out [8,4096,4096] f32.
// out[o][i][j] = (zeroext(seg)[i+ox][j+oy] == seg[i][j]) ? 1.0f : 0.0f
// OFFSETS: (-1,0),(0,-1),(-2,0),(0,-2),(-4,0),(0,-4),(-8,0),(0,-8)
//
// R6: NT-store ablation on the R2 structure (register ring, 8 planes/block,
// single replica). R5 measurement established: reads ~51 MB (near-minimal),
// writes 537 MB (mandatory), kernel ~108 us vs 93 us roofline (87% of
// achievable BW). Only open lever is the store path.

#define IMG_H 4096
#define IMG_W 4096
#define BAND  16

__device__ __forceinline__ float4 ld4(const float* p) { return *(const float4*)p; }
__device__ __forceinline__ void st4(float* p, float4 v) { *(float4*)p = v; }

__device__ __forceinline__ float4 eq4(float4 a, float4 b) {
    return make_float4(a.x == b.x ? 1.0f : 0.0f,
                       a.y == b.y ? 1.0f : 0.0f,
                       a.z == b.z ? 1.0f : 0.0f,
                       a.w == b.w ? 1.0f : 0.0f);
}

__global__ __launch_bounds__(256) void GetAffs_83416854823610_kernel(
        const float* __restrict__ seg, float* __restrict__ out) {
    const int jq = blockIdx.x * 256 + threadIdx.x;  // float4 column group
    const int j  = jq << 2;                         // first of 4 cols
    const int i0 = blockIdx.y * BAND;               // first row of band
    const float4 zero4 = make_float4(0.f, 0.f, 0.f, 0.f);

    // Ring: slot(row r) = (r - i0) & 7. Preload rows i0-8 .. i0-1 (zero if OOB).
    float4 hist[8];
#pragma unroll
    for (int k = 0; k < 8; ++k) {
        const int r = i0 - 8 + k;                   // slot (r - i0) & 7 = k
        hist[k] = (r >= 0) ? ld4(seg + (size_t)r * IMG_W + j) : zero4;
    }

    const size_t HW = (size_t)IMG_H * IMG_W;

#pragma unroll
    for (int u = 0; u < BAND; ++u) {                // row i = i0 + u
        const int i = i0 + u;
        const float* row = seg + (size_t)i * IMG_W;
        const float4 c  = ld4(row + j);
        const float4 l1 = (j >= 4) ? ld4(row + j - 4) : zero4;  // cols j-4..j-1
        const float4 l2 = (j >= 8) ? ld4(row + j - 8) : zero4;  // cols j-8..j-5

        const float4 v1 = hist[(u + 7) & 7];        // row i-1
        const float4 v2 = hist[(u + 6) & 7];        // row i-2
        const float4 v4 = hist[(u + 4) & 7];        // row i-4
        const float4 v8 = hist[u & 7];              // row i-8

        const float4 h1 = make_float4(l1.w, c.x, c.y, c.z);
        const float4 h2 = make_float4(l1.z, l1.w, c.x, c.y);
        const float4 h4 = l1;
        const float4 h8 = l2;

        const size_t base = (size_t)i * IMG_W + (size_t)j;
        st4(out + 0 * HW + base, eq4(v1, c));       // (-1, 0)
        st4(out + 1 * HW + base, eq4(h1, c));       // ( 0,-1)
        st4(out + 2 * HW + base, eq4(v2, c));       // (-2, 0)
        st4(out + 3 * HW + base, eq4(h2, c));       // ( 0,-2)
        st4(out + 4 * HW + base, eq4(v4, c));       // (-4, 0)
        st4(out + 5 * HW + base, eq4(h4, c));       // ( 0,-4)
        st4(out + 6 * HW + base, eq4(v8, c));       // (-8, 0)
        st4(out + 7 * HW + base, eq4(h8, c));       // ( 0,-8)

        hist[u & 7] = c;                            // row i replaces row i-8
    }
}

extern "C" void kernel_launch(void* const* d_in, const int* in_sizes, int n_in,
                              void* d_out, int out_size, void* d_ws, size_t ws_size,
                              hipStream_t stream) {
    const float* seg = (const float*)d_in[0];
    float* out = (float*)d_out;
    // 1024 col-groups / 256 threads = 4 blocks in x; 4096/16 = 256 bands in y.
    dim3 grid((IMG_W / 4) / 256, IMG_H / BAND);
    dim3 block(256);
    GetAffs_83416854823610_kernel<<<grid, block, 0, stream>>>(seg, out);
}

// Round 8
// 581.906 us; speedup vs baseline: 1.5493x; 1.0251x over previous
//
#include <hip/hip_runtime.h>
#include <hip/hip_bf16.h>

// GetAffs: seg [1,1,4096,4096] f32 (integer labels), out [8,4096,4096] f32.
// out[o][i][j] = (zeroext(seg)[i+ox][j+oy] == seg[i][j]) ? 1.0f : 0.0f
// OFFSETS: (-1,0),(0,-1),(-2,0),(0,-2),(-4,0),(0,-4),(-8,0),(0,-8)
//
// R7: revert to R2 (register ring + NT stores — best, 578 us; NT worth ~18 us
// per R6 ablation) with ONE delta: BAND 16->32, halving the ring-preload
// re-read fraction (50% -> 25% extra read requests at band boundaries).
// Ledger from R5 measurement: kernel ~108 us vs ~93 us roofline (537 MB NT
// writes + 51 MB HBM fetch at 6.3 TB/s achievable) -> ~87% of ceiling.

#define IMG_H 4096
#define IMG_W 4096
#define BAND  32

typedef float floatx4 __attribute__((ext_vector_type(4)));

__device__ __forceinline__ float4 ld4(const float* p) { return *(const float4*)p; }

__device__ __forceinline__ void st4_nt(float* p, float4 v) {
    floatx4 x = { v.x, v.y, v.z, v.w };
    __builtin_nontemporal_store(x, (floatx4*)p);
}

__device__ __forceinline__ float4 eq4(float4 a, float4 b) {
    return make_float4(a.x == b.x ? 1.0f : 0.0f,
                       a.y == b.y ? 1.0f : 0.0f,
                       a.z == b.z ? 1.0f : 0.0f,
                       a.w == b.w ? 1.0f : 0.0f);
}

__global__ __launch_bounds__(256) void GetAffs_83416854823610_kernel(
        const float* __restrict__ seg, float* __restrict__ out) {
    const int jq = blockIdx.x * 256 + threadIdx.x;  // float4 column group
    const int j  = jq << 2;                         // first of 4 cols
    const int i0 = blockIdx.y * BAND;               // first row of band
    const float4 zero4 = make_float4(0.f, 0.f, 0.f, 0.f);

    // Ring: slot(row r) = (r - i0) & 7. Preload rows i0-8 .. i0-1 (zero if OOB).
    float4 hist[8];
#pragma unroll
    for (int k = 0; k < 8; ++k) {
        const int r = i0 - 8 + k;                   // slot (r - i0) & 7 = k
        hist[k] = (r >= 0) ? ld4(seg + (size_t)r * IMG_W + j) : zero4;
    }

    const size_t HW = (size_t)IMG_H * IMG_W;

#pragma unroll
    for (int u = 0; u < BAND; ++u) {                // row i = i0 + u
        const int i = i0 + u;
        const float* row = seg + (size_t)i * IMG_W;
        const float4 c  = ld4(row + j);
        const float4 l1 = (j >= 4) ? ld4(row + j - 4) : zero4;  // cols j-4..j-1
        const float4 l2 = (j >= 8) ? ld4(row + j - 8) : zero4;  // cols j-8..j-5

        const float4 v1 = hist[(u + 7) & 7];        // row i-1
        const float4 v2 = hist[(u + 6) & 7];        // row i-2
        const float4 v4 = hist[(u + 4) & 7];        // row i-4
        const float4 v8 = hist[u & 7];              // row i-8

        const float4 h1 = make_float4(l1.w, c.x, c.y, c.z);
        const float4 h2 = make_float4(l1.z, l1.w, c.x, c.y);
        const float4 h4 = l1;
        const float4 h8 = l2;

        const size_t base = (size_t)i * IMG_W + (size_t)j;
        st4_nt(out + 0 * HW + base, eq4(v1, c));    // (-1, 0)
        st4_nt(out + 1 * HW + base, eq4(h1, c));    // ( 0,-1)
        st4_nt(out + 2 * HW + base, eq4(v2, c));    // (-2, 0)
        st4_nt(out + 3 * HW + base, eq4(h2, c));    // ( 0,-2)
        st4_nt(out + 4 * HW + base, eq4(v4, c));    // (-4, 0)
        st4_nt(out + 5 * HW + base, eq4(h4, c));    // ( 0,-4)
        st4_nt(out + 6 * HW + base, eq4(v8, c));    // (-8, 0)
        st4_nt(out + 7 * HW + base, eq4(h8, c));    // ( 0,-8)

        hist[u & 7] = c;                            // row i replaces row i-8
    }
}

extern "C" void kernel_launch(void* const* d_in, const int* in_sizes, int n_in,
                              void* d_out, int out_size, void* d_ws, size_t ws_size,
                              hipStream_t stream) {
    const float* seg = (const float*)d_in[0];
    float* out = (float*)d_out;
    // 1024 col-groups / 256 threads = 4 blocks in x; 4096/32 = 128 bands in y.
    dim3 grid((IMG_W / 4) / 256, IMG_H / BAND);
    dim3 block(256);
    GetAffs_83416854823610_kernel<<<grid, block, 0, stream>>>(seg, out);
}